// Round 4
// baseline (1059.842 us; speedup 1.0000x reference)
//
#include <hip/hip_runtime.h>
#include <hip/hip_bf16.h>

#define NE 4
#define HD 768
#define F2 384
#define F1 192
#define NT 131072
#define TT 128
#define TPE 1024   // tiles per expert = NT/TT

typedef __attribute__((ext_vector_type(8))) short bf16x8;
typedef __attribute__((ext_vector_type(4))) float f32x4;
typedef __attribute__((ext_vector_type(4))) unsigned int u32x4;

// LDS: A double-buffer (GEMM1) overlaid by act (GEMM2); tok at the end.
#define LA0 0u
#define LA1 16384u
#define LACT 0u
#define LTOK 49152u
#define SMEM_BYTES 49664   // ~50KB -> 2 blocks/CU (VGPR-capped)

// workspace layout (bytes)
#define WS_BUCKET_OFF 256
#define WS_GUT_OFF   (WS_BUCKET_OFF + NE*NT*4)
#define WS_DNT_OFF   (WS_GUT_OFF + NE*F2*HD*2)

__device__ __forceinline__ unsigned short f2bf(float x) {
    unsigned int u = __float_as_uint(x);
    return (unsigned short)((u + 0x7fffu + ((u >> 16) & 1u)) >> 16);
}
__device__ __forceinline__ unsigned int pk2(float a, float b) {
    unsigned int ua = __float_as_uint(a), ub = __float_as_uint(b);
    unsigned int lo = (ua + 0x7fffu + ((ua >> 16) & 1u)) >> 16;
    unsigned int hi = (ub + 0x7fffu + ((ub >> 16) & 1u)) & 0xffff0000u;
    return lo | hi;
}

__global__ void route_kernel(const int* __restrict__ ids, int* __restrict__ counts,
                             int* __restrict__ bucket) {
    __shared__ int lc[NE];
    __shared__ int lb[NE];
    int tid = threadIdx.x;
    if (tid < NE) lc[tid] = 0;
    __syncthreads();
    int t = blockIdx.x * blockDim.x + tid;
    int e = ids[t];
    int rank = atomicAdd(&lc[e], 1);
    __syncthreads();
    if (tid < NE) lb[tid] = atomicAdd(&counts[tid], lc[tid]);
    __syncthreads();
    bucket[e * NT + lb[e] + rank] = t;
}

// fp32 -> bf16 with transpose: guT[e][f][k] (k contig), dnT[e][h][f] (f contig)
__global__ void convert_kernel(const float* __restrict__ gu, const float* __restrict__ dn,
                               unsigned short* __restrict__ guT, unsigned short* __restrict__ dnT) {
    int idx = blockIdx.x * blockDim.x + threadIdx.x;
    if (idx < NE * F2 * HD) {
        int k = idx % HD; int r = idx / HD; int f = r % F2; int e = r / F2;
        guT[idx] = f2bf(gu[(e * HD + k) * F2 + f]);
    }
    if (idx < NE * HD * F1) {
        int f = idx % F1; int r = idx / F1; int h = r % HD; int e = r / HD;
        dnT[idx] = f2bf(dn[(e * F1 + f) * HD + h]);
    }
}

__global__ __launch_bounds__(512, 4)
void moe_kernel(const float* __restrict__ hidden, const int* __restrict__ counts,
                const int* __restrict__ bucket, const unsigned short* __restrict__ guT,
                const unsigned short* __restrict__ dnT, float* __restrict__ out)
{
    extern __shared__ __align__(16) unsigned char smem[];

    int e = blockIdx.x >> 10;
    int tile = blockIdx.x & (TPE - 1);
    int n_e = counts[e];
    int t0 = tile * TT;
    if (t0 >= n_e) return;

    int tid = threadIdx.x;
    int lane = tid & 63;
    int w = tid >> 6;
    int rw64 = (w >> 2) << 6;      // row half: 0 or 64
    int w2 = w & 3;                // col quarter
    int lg = lane >> 4;
    int l16 = lane & 15;
    int r7 = l16 & 7;

    int* tokp = (int*)(smem + LTOK);
    if (tid < TT) {
        int idx = t0 + tid; if (idx >= n_e) idx = n_e - 1;
        tokp[tid] = bucket[e * NT + idx];
    }
    __syncthreads();

    // ---- A staging: thread covers row arow, 16 consecutive k at kq*16 ----
    int arow = tid >> 2, kq = tid & 3;
    const float* ab = hidden + (size_t)tokp[arow] * HD + kq * 16;
    unsigned awb0 = (unsigned)(arow * 128 + (((2 * kq)     ^ (arow & 7)) << 4));
    unsigned awb1 = (unsigned)(arow * 128 + (((2 * kq + 1) ^ (arow & 7)) << 4));

    const char* guTc = (const char*)(guT + (size_t)e * F2 * HD);
    const char* dnTc = (const char*)(dnT + (size_t)e * HD * F1);

    // B1 per-lane byte offsets (gate col w2*48.., up col 192+w2*48..: in-reg pairing)
    unsigned b1off[6];
    #pragma unroll
    for (int nt = 0; nt < 6; ++nt) {
        int col = (nt < 3) ? (w2 * 48 + nt * 16 + l16) : (192 + w2 * 48 + (nt - 3) * 16 + l16);
        b1off[nt] = (unsigned)((col * HD + lg * 8) * 2);
    }
    // B2 per-lane byte offsets
    unsigned b2off[6];
    #pragma unroll
    for (int nt = 0; nt < 6; ++nt)
        b2off[nt] = (unsigned)(((w2 * 96 + nt * 16 + l16) * F1 + lg * 8) * 2);

    f32x4 av0, av1, av2, av3;
    auto issueA = [&](int k0) {
        const f32x4* p = (const f32x4*)(ab + k0);
        av0 = p[0]; av1 = p[1]; av2 = p[2]; av3 = p[3];
    };
    auto writeA = [&](unsigned base) {
        u32x4 lo = {pk2(av0.x,av0.y), pk2(av0.z,av0.w), pk2(av1.x,av1.y), pk2(av1.z,av1.w)};
        u32x4 hi = {pk2(av2.x,av2.y), pk2(av2.z,av2.w), pk2(av3.x,av3.y), pk2(av3.z,av3.w)};
        *(u32x4*)(smem + base + awb0) = lo;
        *(u32x4*)(smem + base + awb1) = hi;
    };

    const f32x4 fzero = {0.f, 0.f, 0.f, 0.f};
    f32x4 acc[4][6];
    #pragma unroll
    for (int mt = 0; mt < 4; ++mt)
        #pragma unroll
        for (int nt = 0; nt < 6; ++nt) acc[mt][nt] = fzero;

    // ============ GEMM1: C1[128][384], K=768, BK=64; A via LDS dbuf, B direct L2 ============
    issueA(0); writeA(LA0);
    __syncthreads();

    #pragma unroll 1
    for (int t = 0; t < 12; ++t) {
        unsigned Ab  = (t & 1) ? LA1 : LA0;
        unsigned Abn = (t & 1) ? LA0 : LA1;
        if (t < 11) issueA((t + 1) * 64);

        bf16x8 Bf[2][6];
        #pragma unroll
        for (int kk = 0; kk < 2; ++kk)
            #pragma unroll
            for (int nt = 0; nt < 6; ++nt)
                Bf[kk][nt] = *(const bf16x8*)(guTc + b1off[nt] + (unsigned)((t * 64 + kk * 32) * 2));

        bf16x8 Af[2][4];
        #pragma unroll
        for (int kk = 0; kk < 2; ++kk)
            #pragma unroll
            for (int mt = 0; mt < 4; ++mt) {
                int row = rw64 + mt * 16 + l16;
                Af[kk][mt] = *(const bf16x8*)(smem + Ab + row * 128 + (((kk * 4 + lg) ^ r7) << 4));
            }

        #pragma unroll
        for (int kk = 0; kk < 2; ++kk)
            #pragma unroll
            for (int nt = 0; nt < 6; ++nt)
                #pragma unroll
                for (int mt = 0; mt < 4; ++mt)
                    acc[mt][nt] = __builtin_amdgcn_mfma_f32_16x16x32_bf16(Af[kk][mt], Bf[kk][nt], acc[mt][nt], 0, 0, 0);

        if (t < 11) writeA(Abn);
        __syncthreads();
    }

    // ============ act = silu(gate)*up -> LDS (overlays A buffers) ============
    #pragma unroll
    for (int mt = 0; mt < 4; ++mt)
        #pragma unroll
        for (int nt = 0; nt < 3; ++nt)
            #pragma unroll
            for (int p = 0; p < 4; ++p) {
                float g = acc[mt][nt][p];
                float u = acc[mt][nt + 3][p];
                float s = g / (1.f + __expf(-g));
                int row = rw64 + mt * 16 + 4 * lg + p;
                int f = w2 * 48 + nt * 16 + l16;
                int c = f >> 3;
                unsigned b = (unsigned)(LACT + row * 384 + (((c & 24) | ((c & 7) ^ (row & 7))) << 4) + (f & 7) * 2);
                *(unsigned short*)(smem + b) = f2bf(s * u);
            }
    __syncthreads();

    // ============ GEMM2: out[128][768] = act[128][192] * down; act LDS, B2 direct L2 ============
    #pragma unroll 1
    for (int half = 0; half < 2; ++half) {
        f32x4 c2[4][6];
        #pragma unroll
        for (int mt = 0; mt < 4; ++mt)
            #pragma unroll
            for (int nt = 0; nt < 6; ++nt) c2[mt][nt] = fzero;

        unsigned hoff = (unsigned)(half * F2 * F1 * 2);
        #pragma unroll
        for (int kt = 0; kt < 6; ++kt) {
            bf16x8 B2f[6];
            #pragma unroll
            for (int nt = 0; nt < 6; ++nt)
                B2f[nt] = *(const bf16x8*)(dnTc + hoff + b2off[nt] + (unsigned)(kt * 64));
            bf16x8 A2[4];
            #pragma unroll
            for (int mt = 0; mt < 4; ++mt) {
                int row = rw64 + mt * 16 + l16;
                int c = kt * 4 + lg;
                A2[mt] = *(const bf16x8*)(smem + LACT + row * 384 + (((c & 24) | ((c & 7) ^ r7)) << 4));
            }
            #pragma unroll
            for (int nt = 0; nt < 6; ++nt)
                #pragma unroll
                for (int mt = 0; mt < 4; ++mt)
                    c2[mt][nt] = __builtin_amdgcn_mfma_f32_16x16x32_bf16(A2[mt], B2f[nt], c2[mt][nt], 0, 0, 0);
        }

        #pragma unroll
        for (int mt = 0; mt < 4; ++mt)
            #pragma unroll
            for (int p = 0; p < 4; ++p) {
                int rl = rw64 + mt * 16 + 4 * lg + p;
                if (t0 + rl < n_e) {
                    float* orow = out + (size_t)tokp[rl] * HD + half * F2 + w2 * 96 + l16;
                    #pragma unroll
                    for (int nt = 0; nt < 6; ++nt)
                        orow[nt * 16] = c2[mt][nt][p];
                }
            }
    }
}

extern "C" void kernel_launch(void* const* d_in, const int* in_sizes, int n_in,
                              void* d_out, int out_size, void* d_ws, size_t ws_size,
                              hipStream_t stream) {
    (void)in_sizes; (void)n_in; (void)out_size; (void)ws_size;
    const float* hidden = (const float*)d_in[0];
    const int*   ids    = (const int*)d_in[1];
    const float* gu     = (const float*)d_in[2];
    const float* dn     = (const float*)d_in[3];
    float* out = (float*)d_out;

    char* ws = (char*)d_ws;
    int* counts = (int*)ws;
    int* bucket = (int*)(ws + WS_BUCKET_OFF);
    unsigned short* guT = (unsigned short*)(ws + WS_GUT_OFF);
    unsigned short* dnT = (unsigned short*)(ws + WS_DNT_OFF);

    hipMemsetAsync(d_ws, 0, 64, stream);
    route_kernel<<<NT / 256, 256, 0, stream>>>(ids, counts, bucket);
    convert_kernel<<<(NE * F2 * HD + 255) / 256, 256, 0, stream>>>(gu, dn, guT, dnT);
    moe_kernel<<<NE * TPE, 512, SMEM_BYTES, stream>>>(hidden, counts, bucket, guT, dnT, out);
}

// Round 5
// 423.422 us; speedup vs baseline: 2.5030x; 2.5030x over previous
//
#include <hip/hip_runtime.h>
#include <hip/hip_bf16.h>

#define NE 4
#define HD 768
#define F2 384
#define F1 192
#define NT 131072

typedef __attribute__((ext_vector_type(8))) short bf16x8;
typedef __attribute__((ext_vector_type(4))) float f32x4;
typedef __attribute__((ext_vector_type(4))) unsigned int u32x4;

// workspace layout (bytes)
#define WS_BUCKET_OFF 256
#define WS_GUT_OFF   (WS_BUCKET_OFF + NE*NT*4)
#define WS_DNT_OFF   (WS_GUT_OFF + NE*F2*HD*2)
#define WS_ACT_OFF   (WS_DNT_OFF + NE*F1*HD*2)
#define WS_NEED      ((size_t)WS_ACT_OFF + (size_t)NT*F1*2)

__device__ __forceinline__ unsigned short f2bf(float x) {
    unsigned int u = __float_as_uint(x);
    return (unsigned short)((u + 0x7fffu + ((u >> 16) & 1u)) >> 16);
}
__device__ __forceinline__ unsigned int pk2(float a, float b) {
    unsigned int ua = __float_as_uint(a), ub = __float_as_uint(b);
    unsigned int lo = (ua + 0x7fffu + ((ua >> 16) & 1u)) >> 16;
    unsigned int hi = (ub + 0x7fffu + ((ub >> 16) & 1u)) & 0xffff0000u;
    return lo | hi;
}
#define GLL(srcp, ldsoff) \
    __builtin_amdgcn_global_load_lds((const __attribute__((address_space(1))) void*)(srcp), \
        (__attribute__((address_space(3))) void*)(smem + (ldsoff)), 16, 0, 0)

__global__ void route_kernel(const int* __restrict__ ids, int* __restrict__ counts,
                             int* __restrict__ bucket) {
    __shared__ int lc[NE];
    __shared__ int lb[NE];
    int tid = threadIdx.x;
    if (tid < NE) lc[tid] = 0;
    __syncthreads();
    int t = blockIdx.x * blockDim.x + tid;
    int e = ids[t];
    int rank = atomicAdd(&lc[e], 1);
    __syncthreads();
    if (tid < NE) lb[tid] = atomicAdd(&counts[tid], lc[tid]);
    __syncthreads();
    bucket[e * NT + lb[e] + rank] = t;
}

// fp32 -> bf16 with transpose: guT[e][f][k] (k contig), dnT[e][h][f] (f contig)
__global__ void convert_kernel(const float* __restrict__ gu, const float* __restrict__ dn,
                               unsigned short* __restrict__ guT, unsigned short* __restrict__ dnT) {
    int idx = blockIdx.x * blockDim.x + threadIdx.x;
    if (idx < NE * F2 * HD) {
        int k = idx % HD; int r = idx / HD; int f = r % F2; int e = r / F2;
        guT[idx] = f2bf(gu[(e * HD + k) * F2 + f]);
    }
    if (idx < NE * HD * F1) {
        int f = idx % F1; int r = idx / F1; int h = r % HD; int e = r / HD;
        dnT[idx] = f2bf(dn[(e * F1 + f) * HD + h]);
    }
}

// ===================== GEMM1: act = silu(h*Wg)*(h*Wu), TT=256, Nslice=192 =====================
// LDS: A dbuf 2x32KB [256 rows][8 kchunk swz], B dbuf 2x24KB [192 cols][8 kchunk swz]
#define G1_LA0 0u
#define G1_LA1 32768u
#define G1_LB0 65536u
#define G1_LB1 90112u
#define G_SMEM 114688

__global__ __launch_bounds__(512, 1)
void gemm1_kernel(const float* __restrict__ hidden, const int* __restrict__ counts,
                  const int* __restrict__ bucket, const unsigned short* __restrict__ guT,
                  unsigned short* __restrict__ act)
{
    extern __shared__ __align__(16) unsigned char smem[];
    int bid = blockIdx.x;
    int e = bid >> 10;
    int rem = bid & 1023;
    int tile = rem >> 1, s = rem & 1;
    int n_e = counts[e];
    int t0 = tile * 256;
    if (t0 >= n_e) return;

    int tid = threadIdx.x, lane = tid & 63, w = tid >> 6;
    int rq = w >> 1, ch = w & 1;
    int lg = lane >> 4, l16 = lane & 15;
    const int* bkt = bucket + e * NT;

    // A staging: thread -> row=tid>>1 (0..255), kh=tid&1 (32 k's)
    int arow = tid >> 1, kh = tid & 1;
    int ai = t0 + arow; if (ai >= n_e) ai = n_e - 1;
    const float* aptr = hidden + (size_t)bkt[ai] * HD + kh * 32;
    unsigned awb[4];
    #pragma unroll
    for (int j = 0; j < 4; ++j)
        awb[j] = (unsigned)(arow * 128 + (((kh * 4 + j) ^ (arow & 7)) << 4));

    // B gload: 3 wave-loads; lane -> tile col c, kchunk perm (pre-swizzled source)
    const unsigned short* guTe = guT + (size_t)e * F2 * HD;
    const unsigned short* bsrc[3];
    unsigned bdst[3];
    #pragma unroll
    for (int i = 0; i < 3; ++i) {
        int c = w * 24 + i * 8 + (lane >> 3);
        int kc = lane & 7;
        int gcol = (c < 96) ? (s * 96 + c) : (192 + s * 96 + (c - 96));
        bsrc[i] = guTe + (size_t)gcol * HD + ((kc ^ (c & 7)) * 8);
        bdst[i] = (unsigned)(w * 3072 + i * 1024);
    }

    // frag bases (row&7 == l16&7 and tilecol&7 == l16&7 for all frags)
    unsigned arb[4], brb[6];
    #pragma unroll
    for (int mt = 0; mt < 4; ++mt) arb[mt] = (unsigned)((rq * 64 + mt * 16 + l16) * 128);
    #pragma unroll
    for (int nt = 0; nt < 6; ++nt) {
        int tc = ch * 48 + (nt < 3 ? nt * 16 : 96 + (nt - 3) * 16) + l16;
        brb[nt] = (unsigned)(tc * 128);
    }
    unsigned xs0 = (unsigned)((lg ^ (l16 & 7)) << 4);
    unsigned xs1 = (unsigned)(((4 + lg) ^ (l16 & 7)) << 4);

    f32x4 av[8];
    auto issueA = [&](int k0) {
        const f32x4* p = (const f32x4*)(aptr + k0);
        #pragma unroll
        for (int j = 0; j < 8; ++j) av[j] = p[j];
    };
    auto writeA = [&](unsigned base) {
        #pragma unroll
        for (int j = 0; j < 4; ++j) {
            u32x4 v = { pk2(av[2*j].x, av[2*j].y), pk2(av[2*j].z, av[2*j].w),
                        pk2(av[2*j+1].x, av[2*j+1].y), pk2(av[2*j+1].z, av[2*j+1].w) };
            *(u32x4*)(smem + base + awb[j]) = v;
        }
    };
    auto gloadB = [&](unsigned base, int k0) {
        #pragma unroll
        for (int i = 0; i < 3; ++i) GLL(bsrc[i] + k0, base + bdst[i]);
    };

    const f32x4 fzero = {0.f, 0.f, 0.f, 0.f};
    f32x4 acc[4][6];
    #pragma unroll
    for (int mt = 0; mt < 4; ++mt)
        #pragma unroll
        for (int nt = 0; nt < 6; ++nt) acc[mt][nt] = fzero;

    // prologue
    issueA(0); gloadB(G1_LB0, 0); writeA(G1_LA0);
    __syncthreads();

    #pragma unroll 1
    for (int t = 0; t < 12; ++t) {
        unsigned Ab  = (t & 1) ? G1_LA1 : G1_LA0;
        unsigned Bb  = (t & 1) ? G1_LB1 : G1_LB0;
        unsigned Abn = (t & 1) ? G1_LA0 : G1_LA1;
        unsigned Bbn = (t & 1) ? G1_LB0 : G1_LB1;
        if (t < 11) { gloadB(Bbn, (t + 1) * 64); issueA((t + 1) * 64); }

        #pragma unroll
        for (int kk = 0; kk < 2; ++kk) {
            unsigned xs = kk ? xs1 : xs0;
            bf16x8 Af[4], Bf[6];
            #pragma unroll
            for (int mt = 0; mt < 4; ++mt) Af[mt] = *(const bf16x8*)(smem + Ab + arb[mt] + xs);
            #pragma unroll
            for (int nt = 0; nt < 6; ++nt) Bf[nt] = *(const bf16x8*)(smem + Bb + brb[nt] + xs);
            #pragma unroll
            for (int nt = 0; nt < 6; ++nt)
                #pragma unroll
                for (int mt = 0; mt < 4; ++mt)
                    acc[mt][nt] = __builtin_amdgcn_mfma_f32_16x16x32_bf16(Af[mt], Bf[nt], acc[mt][nt], 0, 0, 0);
        }

        if (t < 11) writeA(Abn);
        __syncthreads();
    }

    // epilogue: silu(gate)*up -> act[token][f] (bf16), masked
    #pragma unroll
    for (int mt = 0; mt < 4; ++mt) {
        #pragma unroll
        for (int p = 0; p < 4; ++p) {
            int r = rq * 64 + mt * 16 + 4 * lg + p;
            int idx = t0 + r;
            if (idx < n_e) {
                unsigned short* arow_p = act + (size_t)bkt[idx] * F1 + s * 96 + ch * 48 + l16;
                #pragma unroll
                for (int nt = 0; nt < 3; ++nt) {
                    float g = acc[mt][nt][p];
                    float u = acc[mt][nt + 3][p];
                    float sv = g / (1.f + __expf(-g));
                    arow_p[nt * 16] = f2bf(sv * u);
                }
            }
        }
    }
}

// ===================== GEMM2: out = act * down, TT=256, Nslice=192, K=192 =====================
__global__ __launch_bounds__(512, 1)
void gemm2_kernel(const int* __restrict__ counts, const int* __restrict__ bucket,
                  const unsigned short* __restrict__ dnT, const unsigned short* __restrict__ act,
                  float* __restrict__ out)
{
    extern __shared__ __align__(16) unsigned char smem[];
    int bid = blockIdx.x;
    int e = bid >> 11;
    int rem = bid & 2047;
    int tile = rem >> 2, sl = rem & 3;
    int n_e = counts[e];
    int t0 = tile * 256;
    if (t0 >= n_e) return;

    int tid = threadIdx.x, lane = tid & 63, w = tid >> 6;
    int rq = w >> 1, ch = w & 1;
    int lg = lane >> 4, l16 = lane & 15;
    const int* bkt = bucket + e * NT;
    const unsigned short* dnTe = dnT + (size_t)e * HD * F1;

    // act gather-gload: 4 wave-loads; lane -> row, kchunk perm
    const unsigned short* asrc[4];
    unsigned adst[4];
    #pragma unroll
    for (int i = 0; i < 4; ++i) {
        int r = w * 32 + i * 8 + (lane >> 3);
        int kc = lane & 7;
        int ri = t0 + r; if (ri >= n_e) ri = n_e - 1;
        asrc[i] = act + (size_t)bkt[ri] * F1 + ((kc ^ (r & 7)) * 8);
        adst[i] = (unsigned)(w * 4096 + i * 1024);
    }
    // B2 gload: 3 wave-loads
    const unsigned short* bsrc[3];
    unsigned bdst[3];
    #pragma unroll
    for (int i = 0; i < 3; ++i) {
        int c = w * 24 + i * 8 + (lane >> 3);
        int kc = lane & 7;
        bsrc[i] = dnTe + (size_t)(sl * 192 + c) * F1 + ((kc ^ (c & 7)) * 8);
        bdst[i] = (unsigned)(w * 3072 + i * 1024);
    }

    unsigned arb[4], brb[6];
    #pragma unroll
    for (int mt = 0; mt < 4; ++mt) arb[mt] = (unsigned)((rq * 64 + mt * 16 + l16) * 128);
    #pragma unroll
    for (int nt = 0; nt < 6; ++nt) brb[nt] = (unsigned)((ch * 96 + nt * 16 + l16) * 128);
    unsigned xs0 = (unsigned)((lg ^ (l16 & 7)) << 4);
    unsigned xs1 = (unsigned)(((4 + lg) ^ (l16 & 7)) << 4);

    auto gload = [&](unsigned Ab, unsigned Bb, int k0) {
        #pragma unroll
        for (int i = 0; i < 4; ++i) GLL(asrc[i] + k0, Ab + adst[i]);
        #pragma unroll
        for (int i = 0; i < 3; ++i) GLL(bsrc[i] + k0, Bb + bdst[i]);
    };

    const f32x4 fzero = {0.f, 0.f, 0.f, 0.f};
    f32x4 acc[4][6];
    #pragma unroll
    for (int mt = 0; mt < 4; ++mt)
        #pragma unroll
        for (int nt = 0; nt < 6; ++nt) acc[mt][nt] = fzero;

    gload(G1_LA0, G1_LB0, 0);
    __syncthreads();

    #pragma unroll 1
    for (int t = 0; t < 3; ++t) {
        unsigned Ab  = (t & 1) ? G1_LA1 : G1_LA0;
        unsigned Bb  = (t & 1) ? G1_LB1 : G1_LB0;
        unsigned Abn = (t & 1) ? G1_LA0 : G1_LA1;
        unsigned Bbn = (t & 1) ? G1_LB0 : G1_LB1;
        if (t < 2) gload(Abn, Bbn, (t + 1) * 64);

        #pragma unroll
        for (int kk = 0; kk < 2; ++kk) {
            unsigned xs = kk ? xs1 : xs0;
            bf16x8 Af[4], Bf[6];
            #pragma unroll
            for (int mt = 0; mt < 4; ++mt) Af[mt] = *(const bf16x8*)(smem + Ab + arb[mt] + xs);
            #pragma unroll
            for (int nt = 0; nt < 6; ++nt) Bf[nt] = *(const bf16x8*)(smem + Bb + brb[nt] + xs);
            #pragma unroll
            for (int nt = 0; nt < 6; ++nt)
                #pragma unroll
                for (int mt = 0; mt < 4; ++mt)
                    acc[mt][nt] = __builtin_amdgcn_mfma_f32_16x16x32_bf16(Af[mt], Bf[nt], acc[mt][nt], 0, 0, 0);
        }
        if (t < 2) __syncthreads();
    }

    // epilogue: scatter fp32 out rows, masked
    #pragma unroll
    for (int mt = 0; mt < 4; ++mt) {
        #pragma unroll
        for (int p = 0; p < 4; ++p) {
            int r = rq * 64 + mt * 16 + 4 * lg + p;
            int idx = t0 + r;
            if (idx < n_e) {
                float* orow = out + (size_t)bkt[idx] * HD + sl * 192 + ch * 96 + l16;
                #pragma unroll
                for (int nt = 0; nt < 6; ++nt)
                    orow[nt * 16] = acc[mt][nt][p];
            }
        }
    }
}

// ===================== fallback: round-3 fused kernel (used if ws too small) =====================
#define FTT 128
#define FTPE 1024
#define F_LA0 0u
#define F_LA1 16384u
#define F_LB0 32768u
#define F_LB1 81920u
#define F_LACT 0u
#define F_LC0 49152u
#define F_LC1 98304u
#define F_LTOK 147456u
#define F_SMEM 147968

__global__ __launch_bounds__(512, 1)
void moe_fused_kernel(const float* __restrict__ hidden, const int* __restrict__ counts,
                      const int* __restrict__ bucket, const unsigned short* __restrict__ guT,
                      const unsigned short* __restrict__ dnT, float* __restrict__ out)
{
    extern __shared__ __align__(16) unsigned char smem[];
    int e = blockIdx.x >> 10;
    int tile = blockIdx.x & (FTPE - 1);
    int n_e = counts[e];
    int t0 = tile * FTT;
    if (t0 >= n_e) return;

    int tid = threadIdx.x;
    int lane = tid & 63;
    int w = tid >> 6;
    int rw64 = (w >> 2) << 6;
    int w2 = w & 3;
    int lg = lane >> 4;
    int l16 = lane & 15;

    int* tokp = (int*)(smem + F_LTOK);
    if (tid < FTT) {
        int idx = t0 + tid; if (idx >= n_e) idx = n_e - 1;
        tokp[tid] = bucket[e * NT + idx];
    }
    __syncthreads();

    int arow = tid >> 2, kq = tid & 3;
    const float* ab = hidden + (size_t)tokp[arow] * HD;
    int colb = tid >> 3, ks = tid & 7;
    const unsigned short* guTe = guT + (size_t)e * F2 * HD;
    const unsigned short* dnTe = dnT + (size_t)e * HD * F1;

    unsigned awb0 = (unsigned)(arow * 128 + ((kq ^ (arow & 7)) << 4));
    unsigned awb1 = (unsigned)(arow * 128 + (((4 + kq) ^ (arow & 7)) << 4));
    unsigned bwb  = (unsigned)(colb * 128 + ((ks ^ (colb & 7)) << 4));

    f32x4 av0, av1, av2, av3;
    bf16x8 bv[6];

    auto issueA = [&](int k0) {
        const float* p = ab + k0 + kq * 8;
        av0 = *(const f32x4*)p;          av1 = *(const f32x4*)(p + 4);
        av2 = *(const f32x4*)(p + 32);   av3 = *(const f32x4*)(p + 36);
    };
    auto writeA = [&](unsigned base) {
        u32x4 lo = {pk2(av0.x,av0.y), pk2(av0.z,av0.w), pk2(av1.x,av1.y), pk2(av1.z,av1.w)};
        u32x4 hi = {pk2(av2.x,av2.y), pk2(av2.z,av2.w), pk2(av3.x,av3.y), pk2(av3.z,av3.w)};
        *(u32x4*)(smem + base + awb0) = lo;
        *(u32x4*)(smem + base + awb1) = hi;
    };
    auto issueB = [&](int k0) {
        #pragma unroll
        for (int jj = 0; jj < 6; ++jj)
            bv[jj] = *(const bf16x8*)(guTe + (size_t)(colb + jj * 64) * HD + k0 + ks * 8);
    };
    auto issueB2 = [&](int half, int sx) {
        #pragma unroll
        for (int jj = 0; jj < 6; ++jj)
            bv[jj] = *(const bf16x8*)(dnTe + (size_t)(half * F2 + colb + jj * 64) * F1 + sx * 64 + ks * 8);
    };
    auto writeB = [&](unsigned base) {
        #pragma unroll
        for (int jj = 0; jj < 6; ++jj)
            *(bf16x8*)(smem + base + bwb + jj * 8192u) = bv[jj];
    };

    unsigned arb[4], brb1[6], b2rb[6], a2rb[4];
    #pragma unroll
    for (int mt = 0; mt < 4; ++mt) {
        arb[mt] = (unsigned)((rw64 + mt * 16 + l16) * 128);
        a2rb[mt] = (unsigned)(F_LACT + (rw64 + mt * 16 + l16) * 384);
    }
    #pragma unroll
    for (int nt = 0; nt < 6; ++nt) {
        int col = w2 * 48 + (nt < 3 ? nt * 16 : 192 + (nt - 3) * 16) + l16;
        brb1[nt] = (unsigned)(col * 128);
        b2rb[nt] = (unsigned)((w2 * 96 + nt * 16 + l16) * 128);
    }
    unsigned xk0 = (unsigned)((lg ^ (l16 & 7)) << 4);
    unsigned xk1 = (unsigned)(((4 + lg) ^ (l16 & 7)) << 4);

    const f32x4 fzero = {0.f, 0.f, 0.f, 0.f};
    f32x4 acc[4][6];
    #pragma unroll
    for (int mt = 0; mt < 4; ++mt)
        #pragma unroll
        for (int nt = 0; nt < 6; ++nt) acc[mt][nt] = fzero;

    issueA(0); issueB(0);
    writeA(F_LA0); writeB(F_LB0);
    __syncthreads();

    #pragma unroll 1
    for (int t = 0; t < 12; ++t) {
        unsigned Ab  = (t & 1) ? F_LA1 : F_LA0;
        unsigned Bb  = (t & 1) ? F_LB1 : F_LB0;
        unsigned Abn = (t & 1) ? F_LA0 : F_LA1;
        unsigned Bbn = (t & 1) ? F_LB0 : F_LB1;
        if (t < 11) { issueA((t + 1) * 64); issueB((t + 1) * 64); }

        bf16x8 Af[2][4], Bf[2][6];
        #pragma unroll
        for (int mt = 0; mt < 4; ++mt) {
            Af[0][mt] = *(const bf16x8*)(smem + Ab + arb[mt] + xk0);
            Af[1][mt] = *(const bf16x8*)(smem + Ab + arb[mt] + xk1);
        }
        #pragma unroll
        for (int nt = 0; nt < 6; ++nt) {
            Bf[0][nt] = *(const bf16x8*)(smem + Bb + brb1[nt] + xk0);
            Bf[1][nt] = *(const bf16x8*)(smem + Bb + brb1[nt] + xk1);
        }
        #pragma unroll
        for (int kk = 0; kk < 2; ++kk)
            #pragma unroll
            for (int nt = 0; nt < 6; ++nt)
                #pragma unroll
                for (int mt = 0; mt < 4; ++mt)
                    acc[mt][nt] = __builtin_amdgcn_mfma_f32_16x16x32_bf16(Af[kk][mt], Bf[kk][nt], acc[mt][nt], 0, 0, 0);

        if (t < 11) { writeA(Abn); writeB(Bbn); }
        __syncthreads();
    }

    issueB2(0, 0);
    #pragma unroll
    for (int mt = 0; mt < 4; ++mt)
        #pragma unroll
        for (int nt = 0; nt < 3; ++nt)
            #pragma unroll
            for (int p = 0; p < 4; ++p) {
                float g = acc[mt][nt][p];
                float u = acc[mt][nt + 3][p];
                float sv = g / (1.f + __expf(-g));
                int row = rw64 + mt * 16 + 4 * lg + p;
                int f = w2 * 48 + nt * 16 + l16;
                int c = f >> 3;
                unsigned b = (unsigned)(F_LACT + row * 384 + (((c & 24) | ((c & 7) ^ (row & 7))) << 4) + (f & 7) * 2);
                *(unsigned short*)(smem + b) = f2bf(sv * u);
            }
    writeB(F_LC0);
    __syncthreads();

    int strow[4][4];
    #pragma unroll
    for (int mt = 0; mt < 4; ++mt)
        #pragma unroll
        for (int p = 0; p < 4; ++p)
            strow[mt][p] = tokp[rw64 + mt * 16 + 4 * lg + p];

    #pragma unroll 1
    for (int half = 0; half < 2; ++half) {
        f32x4 c2[4][6];
        #pragma unroll
        for (int mt = 0; mt < 4; ++mt)
            #pragma unroll
            for (int nt = 0; nt < 6; ++nt) c2[mt][nt] = fzero;

        #pragma unroll
        for (int sx = 0; sx < 3; ++sx) {
            unsigned Cb  = ((half + sx) & 1) ? F_LC1 : F_LC0;
            unsigned Cbn = ((half + sx) & 1) ? F_LC0 : F_LC1;
            int do_next = (sx < 2) || (half == 0);
            if (sx < 2) issueB2(half, sx + 1);
            else if (half == 0) issueB2(1, 0);

            bf16x8 A2[2][4], B2f[2][6];
            #pragma unroll
            for (int mt = 0; mt < 4; ++mt) {
                int c0 = sx * 4;
                A2[0][mt] = *(const bf16x8*)(smem + a2rb[mt] + ((((c0 + lg) & 24) | (((c0 + lg) & 7) ^ (l16 & 7))) << 4));
                A2[1][mt] = *(const bf16x8*)(smem + a2rb[mt] + ((((c0 + 4 + lg) & 24) | (((c0 + 4 + lg) & 7) ^ (l16 & 7))) << 4));
            }
            #pragma unroll
            for (int nt = 0; nt < 6; ++nt) {
                B2f[0][nt] = *(const bf16x8*)(smem + Cb + b2rb[nt] + xk0);
                B2f[1][nt] = *(const bf16x8*)(smem + Cb + b2rb[nt] + xk1);
            }
            #pragma unroll
            for (int kk = 0; kk < 2; ++kk)
                #pragma unroll
                for (int nt = 0; nt < 6; ++nt)
                    #pragma unroll
                    for (int mt = 0; mt < 4; ++mt)
                        c2[mt][nt] = __builtin_amdgcn_mfma_f32_16x16x32_bf16(A2[kk][mt], B2f[kk][nt], c2[mt][nt], 0, 0, 0);

            if (do_next) {
                writeB(Cbn);
                __syncthreads();
            }
        }

        #pragma unroll
        for (int mt = 0; mt < 4; ++mt)
            #pragma unroll
            for (int p = 0; p < 4; ++p) {
                int rl = rw64 + mt * 16 + 4 * lg + p;
                if (t0 + rl < n_e) {
                    float* orow = out + (size_t)strow[mt][p] * HD + half * F2 + w2 * 96 + l16;
                    #pragma unroll
                    for (int nt = 0; nt < 6; ++nt)
                        orow[nt * 16] = c2[mt][nt][p];
                }
            }
    }
}

extern "C" void kernel_launch(void* const* d_in, const int* in_sizes, int n_in,
                              void* d_out, int out_size, void* d_ws, size_t ws_size,
                              hipStream_t stream) {
    (void)in_sizes; (void)n_in; (void)out_size;
    const float* hidden = (const float*)d_in[0];
    const int*   ids    = (const int*)d_in[1];
    const float* gu     = (const float*)d_in[2];
    const float* dn     = (const float*)d_in[3];
    float* out = (float*)d_out;

    char* ws = (char*)d_ws;
    int* counts = (int*)ws;
    int* bucket = (int*)(ws + WS_BUCKET_OFF);
    unsigned short* guT = (unsigned short*)(ws + WS_GUT_OFF);
    unsigned short* dnT = (unsigned short*)(ws + WS_DNT_OFF);

    hipMemsetAsync(d_ws, 0, 64, stream);
    route_kernel<<<NT / 256, 256, 0, stream>>>(ids, counts, bucket);
    convert_kernel<<<(NE * F2 * HD + 255) / 256, 256, 0, stream>>>(gu, dn, guT, dnT);

    if (ws_size >= WS_NEED) {
        unsigned short* act = (unsigned short*)(ws + WS_ACT_OFF);
        gemm1_kernel<<<NE * 1024, 512, G_SMEM, stream>>>(hidden, counts, bucket, guT, act);
        gemm2_kernel<<<NE * 2048, 512, G_SMEM, stream>>>(counts, bucket, dnT, act, out);
    } else {
        moe_fused_kernel<<<NE * FTPE, 512, F_SMEM, stream>>>(hidden, counts, bucket, guT, dnT, out);
    }
}

// Round 6
// 342.655 us; speedup vs baseline: 3.0930x; 1.2357x over previous
//
#include <hip/hip_runtime.h>
#include <hip/hip_bf16.h>

#define NE 4
#define HD 768
#define F2 384
#define F1 192
#define NT 131072
#define TT 128

typedef __attribute__((ext_vector_type(8))) short bf16x8;
typedef __attribute__((ext_vector_type(4))) float f32x4;
typedef __attribute__((ext_vector_type(4))) unsigned int u32x4;

// LDS layout (bytes): GEMM1: A dbuf 2x8KB + B1 dbuf 2x24KB; GEMM2: act 48KB overlays.
#define LA0 0u
#define LA1 8192u
#define LB0 16384u
#define LB1 40960u
#define LACT 0u
#define LTOK 65536u
#define SMEM_BYTES 66048

// workspace layout (bytes)
#define WS_BUCKET_OFF 256
#define WS_B1IMG_OFF (WS_BUCKET_OFF + NE*NT*4)            // 2,097,408
#define WS_DNT2_OFF  (WS_B1IMG_OFF + NE*24*24576)         // +2,359,296
// b1img: per (e,kstep) a 24KB LDS byte-image, 16B unit L: colp=L>>3, slot=L&7,
//        v=slot^(colp&7), tilecol=colp*2+(v>>2), k=kstep*32+(v&3)*8
// dnT2:  [e][f>>3][h][f&7] so a 4-lane lg-group reads 256B contiguous

__device__ __forceinline__ unsigned short f2bf(float x) {
    unsigned int u = __float_as_uint(x);
    return (unsigned short)((u + 0x7fffu + ((u >> 16) & 1u)) >> 16);
}
__device__ __forceinline__ unsigned int pk2(float a, float b) {
    unsigned int ua = __float_as_uint(a), ub = __float_as_uint(b);
    unsigned int lo = (ua + 0x7fffu + ((ua >> 16) & 1u)) >> 16;
    unsigned int hi = (ub + 0x7fffu + ((ub >> 16) & 1u)) & 0xffff0000u;
    return lo | hi;
}
#define GLL(srcp, ldsoff) \
    __builtin_amdgcn_global_load_lds((const __attribute__((address_space(1))) void*)(srcp), \
        (__attribute__((address_space(3))) void*)(smem + (ldsoff)), 16, 0, 0)

__global__ void route_kernel(const int* __restrict__ ids, int* __restrict__ counts,
                             int* __restrict__ bucket) {
    __shared__ int lc[NE];
    __shared__ int lb[NE];
    int tid = threadIdx.x;
    if (tid < NE) lc[tid] = 0;
    __syncthreads();
    int t = blockIdx.x * blockDim.x + tid;
    int e = ids[t];
    int rank = atomicAdd(&lc[e], 1);
    __syncthreads();
    if (tid < NE) lb[tid] = atomicAdd(&counts[tid], lc[tid]);
    __syncthreads();
    bucket[e * NT + lb[e] + rank] = t;
}

// Build the pre-swizzled B1 LDS image: one thread per 16B unit.
__global__ void b1img_kernel(const float* __restrict__ gu, unsigned short* __restrict__ b1img) {
    int idx = blockIdx.x * 256 + threadIdx.x;      // NE*24*1536 = 147456
    int L = idx % 1536;
    int es = idx / 1536;
    int kstep = es % 24, e = es / 24;
    int colp = L >> 3, slot = L & 7;
    int v = slot ^ (colp & 7);
    int tc = colp * 2 + (v >> 2);
    int kb = kstep * 32 + (v & 3) * 8;
    const float* src = gu + ((size_t)(e * HD + kb)) * F2 + tc;
    unsigned short o[8];
    #pragma unroll
    for (int j = 0; j < 8; ++j) o[j] = f2bf(src[(size_t)j * F2]);
    *(bf16x8*)(b1img + ((size_t)idx) * 8) = *(const bf16x8*)o;
}

// dnT2[e][f>>3][h][f&7] <- dn[e][f][h]
__global__ void dnt2_kernel(const float* __restrict__ dn, unsigned short* __restrict__ dnt2) {
    int idx = blockIdx.x * 256 + threadIdx.x;      // NE*F1*HD = 589824
    int h = idx % HD; int rf = idx / HD; int f = rf % F1; int e = rf / F1;
    dnt2[(((size_t)e * 24 + (f >> 3)) * HD + h) * 8 + (f & 7)] = f2bf(dn[idx]);
}

__global__ __launch_bounds__(512, 2)
void moe_kernel(const float* __restrict__ hidden, const int* __restrict__ counts,
                const int* __restrict__ bucket, const unsigned short* __restrict__ b1img,
                const unsigned short* __restrict__ dnt2, float* __restrict__ out)
{
    extern __shared__ __align__(16) unsigned char smem[];

    // exact block -> (expert, tile) mapping via prefix over counts
    int rem = blockIdx.x, e, n_e = 0;
    for (e = 0; e < NE; ++e) {
        n_e = counts[e];
        int ntiles = (n_e + TT - 1) >> 7;
        if (rem < ntiles) break;
        rem -= ntiles;
    }
    if (e >= NE) return;
    int t0 = rem << 7;

    int tid = threadIdx.x;
    int lane = tid & 63;
    int w = tid >> 6;
    int rw64 = (w >> 2) << 6;      // row half 0/64
    int cq = w & 3;                // col quarter
    int lg = lane >> 4;
    int l16 = lane & 15;

    int* tokp = (int*)(smem + LTOK);
    if (tid < TT) {
        int idx = t0 + tid; if (idx >= n_e) idx = n_e - 1;
        tokp[tid] = bucket[e * NT + idx];
    }
    __syncthreads();

    // ---- A staging: thread -> (row=tid>>2, kq=tid&3), 8 fp32 per step ----
    int arow = tid >> 2, kq = tid & 3;
    const float* aptr = hidden + (size_t)tokp[arow] * HD + kq * 8;
    unsigned awb = (unsigned)((tid >> 3) * 128 +
                   (((kq + ((arow & 1) << 2)) ^ ((tid >> 3) & 7)) << 4));

    // ---- B1 GLL: 3 wave-loads/step from pre-swizzled image (linear 1KB each) ----
    const unsigned short* gls = b1img + (size_t)e * 24 * 12288 + (w * 3) * 512 + lane * 8;
    unsigned gld = (unsigned)(w * 3) * 1024u;

    // ---- fragment read addressing (slot-XOR, proven 0-conflict in r5) ----
    unsigned laneoff = (unsigned)(((l16 >> 1) << 7) +
                       (((lg + ((l16 & 1) << 2)) ^ (l16 >> 1)) << 4));
    unsigned arb[4], brb[6];
    #pragma unroll
    for (int mt = 0; mt < 4; ++mt)
        arb[mt] = (unsigned)((rw64 + mt * 16) * 64) + laneoff;
    #pragma unroll
    for (int nt = 0; nt < 6; ++nt) {
        int tcb = (nt < 3) ? (cq * 48 + nt * 16) : (192 + cq * 48 + (nt - 3) * 16);
        brb[nt] = (unsigned)(tcb * 64) + laneoff;
    }

    f32x4 av0, av1;
    auto issueA = [&](int k0) {
        const f32x4* p = (const f32x4*)(aptr + k0);
        av0 = p[0]; av1 = p[1];
    };
    auto writeA = [&](unsigned base) {
        u32x4 vv = {pk2(av0.x,av0.y), pk2(av0.z,av0.w), pk2(av1.x,av1.y), pk2(av1.z,av1.w)};
        *(u32x4*)(smem + base + awb) = vv;
    };

    const f32x4 fzero = {0.f, 0.f, 0.f, 0.f};
    f32x4 acc[4][6];
    #pragma unroll
    for (int mt = 0; mt < 4; ++mt)
        #pragma unroll
        for (int nt = 0; nt < 6; ++nt) acc[mt][nt] = fzero;

    // ================= GEMM1: C1[128][384], K=768, BK=32 =================
    issueA(0);
    #pragma unroll
    for (int i = 0; i < 3; ++i) GLL(gls + i * 512, LB0 + gld + i * 1024u);
    writeA(LA0);
    __syncthreads();

    #pragma unroll 1
    for (int t = 0; t < 24; ++t) {
        unsigned Ab  = (t & 1) ? LA1 : LA0;
        unsigned Bb  = (t & 1) ? LB1 : LB0;
        unsigned Abn = (t & 1) ? LA0 : LA1;
        unsigned Bbn = (t & 1) ? LB0 : LB1;
        if (t < 23) {
            issueA((t + 1) * 32);   // A loads FIRST (older in vmcnt queue)
            #pragma unroll
            for (int i = 0; i < 3; ++i) GLL(gls + (t + 1) * 12288 + i * 512, Bbn + gld + i * 1024u);
        }

        bf16x8 Af[4];
        #pragma unroll
        for (int mt = 0; mt < 4; ++mt) Af[mt] = *(const bf16x8*)(smem + Ab + arb[mt]);
        #pragma unroll
        for (int nt = 0; nt < 6; ++nt) {
            bf16x8 Bf = *(const bf16x8*)(smem + Bb + brb[nt]);
            #pragma unroll
            for (int mt = 0; mt < 4; ++mt)
                acc[mt][nt] = __builtin_amdgcn_mfma_f32_16x16x32_bf16(Af[mt], Bf, acc[mt][nt], 0, 0, 0);
        }

        if (t < 23) writeA(Abn);
        __syncthreads();
    }

    // ================= act = silu(gate)*up -> LDS (overlays GEMM1 buffers) =================
    #pragma unroll
    for (int mt = 0; mt < 4; ++mt)
        #pragma unroll
        for (int nt = 0; nt < 3; ++nt)
            #pragma unroll
            for (int p = 0; p < 4; ++p) {
                float g = acc[mt][nt][p];
                float u = acc[mt][nt + 3][p];
                float s = g / (1.f + __expf(-g));
                int row = rw64 + mt * 16 + 4 * lg + p;
                int f = cq * 48 + nt * 16 + l16;
                int c = f >> 3;
                unsigned b = (unsigned)(LACT + row * 384 + (((c & 24) | ((c & 7) ^ (row & 7))) << 4) + (f & 7) * 2);
                *(unsigned short*)(smem + b) = f2bf(s * u);
            }
    __syncthreads();

    // ================= GEMM2: out[128][768] = act[128][192] * down =================
    const unsigned short* d2e = dnt2 + (size_t)e * 24 * HD * 8;
    unsigned hb_lane = (unsigned)(cq * 96 + l16);

    #pragma unroll 1
    for (int half = 0; half < 2; ++half) {
        f32x4 c2[4][6];
        #pragma unroll
        for (int mt = 0; mt < 4; ++mt)
            #pragma unroll
            for (int nt = 0; nt < 6; ++nt) c2[mt][nt] = fzero;

        unsigned hbase = (unsigned)half * 384u + hb_lane;
        #pragma unroll
        for (int kt = 0; kt < 6; ++kt) {
            int c = kt * 4 + lg;
            unsigned a2sl = (unsigned)(((c & 24) | ((c & 7) ^ (l16 & 7))) << 4);
            bf16x8 A2[4];
            #pragma unroll
            for (int mt = 0; mt < 4; ++mt)
                A2[mt] = *(const bf16x8*)(smem + LACT + (rw64 + mt * 16 + l16) * 384 + a2sl);
            #pragma unroll
            for (int nt = 0; nt < 6; ++nt) {
                bf16x8 B2 = *(const bf16x8*)(d2e + ((size_t)c * HD + hbase + nt * 16) * 8);
                #pragma unroll
                for (int mt = 0; mt < 4; ++mt)
                    c2[mt][nt] = __builtin_amdgcn_mfma_f32_16x16x32_bf16(A2[mt], B2, c2[mt][nt], 0, 0, 0);
            }
        }

        #pragma unroll
        for (int mt = 0; mt < 4; ++mt)
            #pragma unroll
            for (int p = 0; p < 4; ++p) {
                int row = rw64 + mt * 16 + 4 * lg + p;
                if (t0 + row < n_e) {
                    float* orow = out + (size_t)tokp[row] * HD + half * 384 + cq * 96 + l16;
                    #pragma unroll
                    for (int nt = 0; nt < 6; ++nt)
                        orow[nt * 16] = c2[mt][nt][p];
                }
            }
    }
}

extern "C" void kernel_launch(void* const* d_in, const int* in_sizes, int n_in,
                              void* d_out, int out_size, void* d_ws, size_t ws_size,
                              hipStream_t stream) {
    (void)in_sizes; (void)n_in; (void)out_size; (void)ws_size;
    const float* hidden = (const float*)d_in[0];
    const int*   ids    = (const int*)d_in[1];
    const float* gu     = (const float*)d_in[2];
    const float* dn     = (const float*)d_in[3];
    float* out = (float*)d_out;

    char* ws = (char*)d_ws;
    int* counts = (int*)ws;
    int* bucket = (int*)(ws + WS_BUCKET_OFF);
    unsigned short* b1img = (unsigned short*)(ws + WS_B1IMG_OFF);
    unsigned short* dnt2  = (unsigned short*)(ws + WS_DNT2_OFF);

    hipMemsetAsync(d_ws, 0, 64, stream);
    route_kernel<<<NT / 256, 256, 0, stream>>>(ids, counts, bucket);
    b1img_kernel<<<576, 256, 0, stream>>>(gu, b1img);       // NE*24*1536 threads
    dnt2_kernel<<<2304, 256, 0, stream>>>(dn, dnt2);        // NE*F1*HD threads
    moe_kernel<<<1028, 512, SMEM_BYTES, stream>>>(hidden, counts, bucket, b1img, dnt2, out);
}

// Round 7
// 323.954 us; speedup vs baseline: 3.2716x; 1.0577x over previous
//
#include <hip/hip_runtime.h>
#include <hip/hip_bf16.h>

#define NE 4
#define HD 768
#define F2 384
#define F1 192
#define NT 131072
#define TT 128

typedef __attribute__((ext_vector_type(8))) short bf16x8;
typedef __attribute__((ext_vector_type(4))) float f32x4;
typedef __attribute__((ext_vector_type(4))) unsigned int u32x4;

// LDS layout (bytes):
//  GEMM1: A dbuf 0..16K, B1 dbuf 16K..64K
//  GEMM2: act 0..48K (overlays dead A/B1), B2 single buf 48K..72K
#define LA0 0u
#define LA1 8192u
#define LB0 16384u
#define LB1 40960u
#define LACT 0u
#define LB2 49152u
#define LTOK 73728u
#define SMEM_BYTES 74240

// workspace layout (bytes)
#define WS_BUCKET_OFF 256
#define WS_B1IMG_OFF (WS_BUCKET_OFF + NE*NT*4)            // B1 image: NE*24*24576 = 2.36 MB
#define WS_DNIMG_OFF (WS_B1IMG_OFF + NE*24*24576)         // B2 image: NE*2*6*24576 = 1.18 MB
// b1img: per (e,kstep) a 24KB LDS byte-image, 16B unit L: colp=L>>3, slot=L&7,
//        v=slot^(colp&7), tilecol=colp*2+(v>>2), k=kstep*32+(v&3)*8
// dnimg: per (e,half,kt) a 24KB image, same unit mapping; col=h within half, k over 192

__device__ __forceinline__ unsigned short f2bf(float x) {
    unsigned int u = __float_as_uint(x);
    return (unsigned short)((u + 0x7fffu + ((u >> 16) & 1u)) >> 16);
}
__device__ __forceinline__ unsigned int pk2(float a, float b) {
    unsigned int ua = __float_as_uint(a), ub = __float_as_uint(b);
    unsigned int lo = (ua + 0x7fffu + ((ua >> 16) & 1u)) >> 16;
    unsigned int hi = (ub + 0x7fffu + ((ub >> 16) & 1u)) & 0xffff0000u;
    return lo | hi;
}
#define GLL(srcp, ldsoff) \
    __builtin_amdgcn_global_load_lds((const __attribute__((address_space(1))) void*)(srcp), \
        (__attribute__((address_space(3))) void*)(smem + (ldsoff)), 16, 0, 0)

__global__ void route_kernel(const int* __restrict__ ids, int* __restrict__ counts,
                             int* __restrict__ bucket) {
    __shared__ int lc[NE];
    __shared__ int lb[NE];
    int tid = threadIdx.x;
    if (tid < NE) lc[tid] = 0;
    __syncthreads();
    int t = blockIdx.x * blockDim.x + tid;
    int e = ids[t];
    int rank = atomicAdd(&lc[e], 1);
    __syncthreads();
    if (tid < NE) lb[tid] = atomicAdd(&counts[tid], lc[tid]);
    __syncthreads();
    bucket[e * NT + lb[e] + rank] = t;
}

// Build the pre-swizzled B1 LDS image: one thread per 16B unit.
__global__ void b1img_kernel(const float* __restrict__ gu, unsigned short* __restrict__ b1img) {
    int idx = blockIdx.x * 256 + threadIdx.x;      // NE*24*1536 = 147456
    int L = idx % 1536;
    int es = idx / 1536;
    int kstep = es % 24, e = es / 24;
    int colp = L >> 3, slot = L & 7;
    int v = slot ^ (colp & 7);
    int tc = colp * 2 + (v >> 2);
    int kb = kstep * 32 + (v & 3) * 8;
    const float* src = gu + ((size_t)(e * HD + kb)) * F2 + tc;
    unsigned short o[8];
    #pragma unroll
    for (int j = 0; j < 8; ++j) o[j] = f2bf(src[(size_t)j * F2]);
    *(bf16x8*)(b1img + ((size_t)idx) * 8) = *(const bf16x8*)o;
}

// Build the pre-swizzled B2 (down-proj) LDS image: one thread per 16B unit.
__global__ void dnimg_kernel(const float* __restrict__ dn, unsigned short* __restrict__ dnimg) {
    int idx = blockIdx.x * 256 + threadIdx.x;      // NE*2*6*1536 = 73728
    int L = idx % 1536;
    int r = idx / 1536;
    int kt = r % 6; r /= 6;
    int half = r & 1; int e = r >> 1;
    int colp = L >> 3, slot = L & 7;
    int v = slot ^ (colp & 7);
    int tc = colp * 2 + (v >> 2);                  // h-col within half (0..383)
    int kb = kt * 32 + (v & 3) * 8;                // f-index (0..191)
    const float* src = dn + ((size_t)(e * F1 + kb)) * HD + half * 384 + tc;
    unsigned short o[8];
    #pragma unroll
    for (int j = 0; j < 8; ++j) o[j] = f2bf(src[(size_t)j * HD]);
    *(bf16x8*)(dnimg + ((size_t)idx) * 8) = *(const bf16x8*)o;
}

__global__ __launch_bounds__(512, 2)
void moe_kernel(const float* __restrict__ hidden, const int* __restrict__ counts,
                const int* __restrict__ bucket, const unsigned short* __restrict__ b1img,
                const unsigned short* __restrict__ dnimg, float* __restrict__ out)
{
    extern __shared__ __align__(16) unsigned char smem[];

    // exact block -> (expert, tile) mapping via prefix over counts
    int rem = blockIdx.x, e, n_e = 0;
    for (e = 0; e < NE; ++e) {
        n_e = counts[e];
        int ntiles = (n_e + TT - 1) >> 7;
        if (rem < ntiles) break;
        rem -= ntiles;
    }
    if (e >= NE) return;
    int t0 = rem << 7;

    int tid = threadIdx.x;
    int lane = tid & 63;
    int w = tid >> 6;
    int rw64 = (w >> 2) << 6;      // row half 0/64
    int cq = w & 3;                // col quarter
    int lg = lane >> 4;
    int l16 = lane & 15;

    int* tokp = (int*)(smem + LTOK);
    if (tid < TT) {
        int idx = t0 + tid; if (idx >= n_e) idx = n_e - 1;
        tokp[tid] = bucket[e * NT + idx];
    }
    __syncthreads();

    // ---- A staging: thread -> (row=tid>>2, kq=tid&3), 8 fp32 per step ----
    int arow = tid >> 2, kq = tid & 3;
    const float* aptr = hidden + (size_t)tokp[arow] * HD + kq * 8;
    unsigned awb = (unsigned)((tid >> 3) * 128 +
                   (((kq + ((arow & 1) << 2)) ^ ((tid >> 3) & 7)) << 4));

    // ---- B1 GLL: 3 wave-loads/step from pre-swizzled image (linear 1KB each) ----
    const unsigned short* gls = b1img + (size_t)e * 24 * 12288 + (w * 3) * 512 + lane * 8;
    unsigned gld = (unsigned)(w * 3) * 1024u;

    // ---- B2 GLL source base ----
    const unsigned short* gls2 = dnimg + (size_t)e * 12 * 12288 + (w * 3) * 512 + lane * 8;

    // ---- fragment read addressing (slot-XOR, proven 0-conflict) ----
    unsigned laneoff = (unsigned)(((l16 >> 1) << 7) +
                       (((lg + ((l16 & 1) << 2)) ^ (l16 >> 1)) << 4));
    unsigned arb[4], brb[6], b2rb[6];
    #pragma unroll
    for (int mt = 0; mt < 4; ++mt)
        arb[mt] = (unsigned)((rw64 + mt * 16) * 64) + laneoff;
    #pragma unroll
    for (int nt = 0; nt < 6; ++nt) {
        int tcb = (nt < 3) ? (cq * 48 + nt * 16) : (192 + cq * 48 + (nt - 3) * 16);
        brb[nt] = (unsigned)(tcb * 64) + laneoff;
        b2rb[nt] = LB2 + (unsigned)((cq * 96 + nt * 16) * 64) + laneoff;
    }

    f32x4 av0, av1;
    auto issueA = [&](int k0) {
        const f32x4* p = (const f32x4*)(aptr + k0);
        av0 = p[0]; av1 = p[1];
    };
    auto writeA = [&](unsigned base) {
        u32x4 vv = {pk2(av0.x,av0.y), pk2(av0.z,av0.w), pk2(av1.x,av1.y), pk2(av1.z,av1.w)};
        *(u32x4*)(smem + base + awb) = vv;
    };

    const f32x4 fzero = {0.f, 0.f, 0.f, 0.f};
    f32x4 acc[4][6];
    #pragma unroll
    for (int mt = 0; mt < 4; ++mt)
        #pragma unroll
        for (int nt = 0; nt < 6; ++nt) acc[mt][nt] = fzero;

    // ================= GEMM1: C1[128][384], K=768, BK=32 =================
    issueA(0);
    #pragma unroll
    for (int i = 0; i < 3; ++i) GLL(gls + i * 512, LB0 + gld + i * 1024u);
    writeA(LA0);
    __syncthreads();

    #pragma unroll 1
    for (int t = 0; t < 24; ++t) {
        unsigned Ab  = (t & 1) ? LA1 : LA0;
        unsigned Bb  = (t & 1) ? LB1 : LB0;
        unsigned Abn = (t & 1) ? LA0 : LA1;
        unsigned Bbn = (t & 1) ? LB0 : LB1;
        if (t < 23) {
            issueA((t + 1) * 32);   // A loads FIRST (older in vmcnt queue)
            #pragma unroll
            for (int i = 0; i < 3; ++i) GLL(gls + (t + 1) * 12288 + i * 512, Bbn + gld + i * 1024u);
        }

        bf16x8 Af[4];
        #pragma unroll
        for (int mt = 0; mt < 4; ++mt) Af[mt] = *(const bf16x8*)(smem + Ab + arb[mt]);
        __builtin_amdgcn_s_setprio(1);
        #pragma unroll
        for (int nt = 0; nt < 6; ++nt) {
            bf16x8 Bf = *(const bf16x8*)(smem + Bb + brb[nt]);
            #pragma unroll
            for (int mt = 0; mt < 4; ++mt)
                acc[mt][nt] = __builtin_amdgcn_mfma_f32_16x16x32_bf16(Af[mt], Bf, acc[mt][nt], 0, 0, 0);
        }
        __builtin_amdgcn_s_setprio(0);

        if (t < 23) writeA(Abn);
        __syncthreads();
    }

    // ================= act = silu(gate)*up -> LDS; prefetch B2(half0,kt0) =================
    #pragma unroll
    for (int i = 0; i < 3; ++i) GLL(gls2 + i * 512, LB2 + gld + i * 1024u);

    #pragma unroll
    for (int mt = 0; mt < 4; ++mt)
        #pragma unroll
        for (int nt = 0; nt < 3; ++nt)
            #pragma unroll
            for (int p = 0; p < 4; ++p) {
                float g = acc[mt][nt][p];
                float u = acc[mt][nt + 3][p];
                float s = g / (1.f + __expf(-g));
                int row = rw64 + mt * 16 + 4 * lg + p;
                int f = cq * 48 + nt * 16 + l16;
                int c = f >> 3;
                unsigned b = (unsigned)(LACT + row * 384 + (((c & 24) | ((c & 7) ^ (row & 7))) << 4) + (f & 7) * 2);
                *(unsigned short*)(smem + b) = f2bf(s * u);
            }
    __syncthreads();    // act visible + B2(0,0) staged

    // ================= GEMM2: out[128][768] = act[128][192] * down =================
    #pragma unroll 1
    for (int half = 0; half < 2; ++half) {
        f32x4 c2[4][6];
        #pragma unroll
        for (int mt = 0; mt < 4; ++mt)
            #pragma unroll
            for (int nt = 0; nt < 6; ++nt) c2[mt][nt] = fzero;

        #pragma unroll 1
        for (int kt = 0; kt < 6; ++kt) {
            // read frags from staged B2 + act
            int c = kt * 4 + lg;
            unsigned a2sl = (unsigned)(((c & 24) | ((c & 7) ^ (l16 & 7))) << 4);
            bf16x8 A2[4], B2f[6];
            #pragma unroll
            for (int mt = 0; mt < 4; ++mt)
                A2[mt] = *(const bf16x8*)(smem + LACT + (rw64 + mt * 16 + l16) * 384 + a2sl);
            #pragma unroll
            for (int nt = 0; nt < 6; ++nt)
                B2f[nt] = *(const bf16x8*)(smem + b2rb[nt]);
            __syncthreads();   // all waves done reading LB2 (syncthreads drains lgkm)

            // stage next (half,kt) while MFMAs run
            int nidx = half * 6 + kt + 1;          // next linear stage index
            if (nidx < 12) {
                #pragma unroll
                for (int i = 0; i < 3; ++i)
                    GLL(gls2 + (size_t)nidx * 12288 + i * 512, LB2 + gld + i * 1024u);
            }

            __builtin_amdgcn_s_setprio(1);
            #pragma unroll
            for (int nt = 0; nt < 6; ++nt)
                #pragma unroll
                for (int mt = 0; mt < 4; ++mt)
                    c2[mt][nt] = __builtin_amdgcn_mfma_f32_16x16x32_bf16(A2[mt], B2f[nt], c2[mt][nt], 0, 0, 0);
            __builtin_amdgcn_s_setprio(0);

            __syncthreads();   // drains GLL(next) — mostly covered by the MFMA cluster
        }

        #pragma unroll
        for (int mt = 0; mt < 4; ++mt)
            #pragma unroll
            for (int p = 0; p < 4; ++p) {
                int row = rw64 + mt * 16 + 4 * lg + p;
                if (t0 + row < n_e) {
                    float* orow = out + (size_t)tokp[row] * HD + half * 384 + cq * 96 + l16;
                    #pragma unroll
                    for (int nt = 0; nt < 6; ++nt)
                        orow[nt * 16] = c2[mt][nt][p];
                }
            }
    }
}

extern "C" void kernel_launch(void* const* d_in, const int* in_sizes, int n_in,
                              void* d_out, int out_size, void* d_ws, size_t ws_size,
                              hipStream_t stream) {
    (void)in_sizes; (void)n_in; (void)out_size; (void)ws_size;
    const float* hidden = (const float*)d_in[0];
    const int*   ids    = (const int*)d_in[1];
    const float* gu     = (const float*)d_in[2];
    const float* dn     = (const float*)d_in[3];
    float* out = (float*)d_out;

    char* ws = (char*)d_ws;
    int* counts = (int*)ws;
    int* bucket = (int*)(ws + WS_BUCKET_OFF);
    unsigned short* b1img = (unsigned short*)(ws + WS_B1IMG_OFF);
    unsigned short* dnimg = (unsigned short*)(ws + WS_DNIMG_OFF);

    hipMemsetAsync(d_ws, 0, 64, stream);
    route_kernel<<<NT / 256, 256, 0, stream>>>(ids, counts, bucket);
    b1img_kernel<<<576, 256, 0, stream>>>(gu, b1img);       // NE*24*1536 units
    dnimg_kernel<<<288, 256, 0, stream>>>(dn, dnimg);       // NE*2*6*1536 units
    moe_kernel<<<1028, 512, SMEM_BYTES, stream>>>(hidden, counts, bucket, b1img, dnimg, out);
}

// Round 8
// 287.166 us; speedup vs baseline: 3.6907x; 1.1281x over previous
//
#include <hip/hip_runtime.h>
#include <hip/hip_bf16.h>

#define NE 4
#define HD 768
#define F2 384
#define F1 192
#define NT 131072
#define TT 128

typedef __attribute__((ext_vector_type(8))) short bf16x8;
typedef __attribute__((ext_vector_type(4))) float f32x4;
typedef __attribute__((ext_vector_type(4))) unsigned int u32x4;

// LDS layout (bytes):
//  GEMM1: A dbuf 0..16K ; B1 quad-buf 16K..112K (4 x 24K)
//  GEMM2: act 0..48K (overlays A + B1[0..1]) ; B2 tri-buf 48K..120K (3 x 24K)
//  tok 120K.. (survives whole kernel)
#define SMEM_BYTES 123392
#define LTOK 122880u

// workspace layout (bytes)
#define WS_BUCKET_OFF 256
#define WS_B1IMG_OFF (WS_BUCKET_OFF + NE*NT*4)            // B1 image: NE*24*24576 = 2.36 MB
#define WS_DNIMG_OFF (WS_B1IMG_OFF + NE*24*24576)         // B2 image: NE*2*6*24576 = 1.18 MB
// b1img: per (e,kstep) a 24KB LDS byte-image, 16B unit L: colp=L>>3, slot=L&7,
//        v=slot^(colp&7), tilecol=colp*2+(v>>2), k=kstep*32+(v&3)*8
// dnimg: per (e,half,kt) a 24KB image, same unit mapping; col=h within half, k over 192

__device__ __forceinline__ unsigned short f2bf(float x) {
    unsigned int u = __float_as_uint(x);
    return (unsigned short)((u + 0x7fffu + ((u >> 16) & 1u)) >> 16);
}
__device__ __forceinline__ unsigned int pk2(float a, float b) {
    unsigned int ua = __float_as_uint(a), ub = __float_as_uint(b);
    unsigned int lo = (ua + 0x7fffu + ((ua >> 16) & 1u)) >> 16;
    unsigned int hi = (ub + 0x7fffu + ((ub >> 16) & 1u)) & 0xffff0000u;
    return lo | hi;
}
#define GLL(srcp, ldsoff) \
    __builtin_amdgcn_global_load_lds((const __attribute__((address_space(1))) void*)(srcp), \
        (__attribute__((address_space(3))) void*)(smem + (ldsoff)), 16, 0, 0)

__global__ void route_kernel(const int* __restrict__ ids, int* __restrict__ counts,
                             int* __restrict__ bucket) {
    __shared__ int lc[NE];
    __shared__ int lb[NE];
    int tid = threadIdx.x;
    if (tid < NE) lc[tid] = 0;
    __syncthreads();
    int t = blockIdx.x * blockDim.x + tid;
    int e = ids[t];
    int rank = atomicAdd(&lc[e], 1);
    __syncthreads();
    if (tid < NE) lb[tid] = atomicAdd(&counts[tid], lc[tid]);
    __syncthreads();
    bucket[e * NT + lb[e] + rank] = t;
}

// Build the pre-swizzled B1 LDS image: one thread per 16B unit.
__global__ void b1img_kernel(const float* __restrict__ gu, unsigned short* __restrict__ b1img) {
    int idx = blockIdx.x * 256 + threadIdx.x;      // NE*24*1536 = 147456
    int L = idx % 1536;
    int es = idx / 1536;
    int kstep = es % 24, e = es / 24;
    int colp = L >> 3, slot = L & 7;
    int v = slot ^ (colp & 7);
    int tc = colp * 2 + (v >> 2);
    int kb = kstep * 32 + (v & 3) * 8;
    const float* src = gu + ((size_t)(e * HD + kb)) * F2 + tc;
    unsigned short o[8];
    #pragma unroll
    for (int j = 0; j < 8; ++j) o[j] = f2bf(src[(size_t)j * F2]);
    *(bf16x8*)(b1img + ((size_t)idx) * 8) = *(const bf16x8*)o;
}

// Build the pre-swizzled B2 (down-proj) LDS image: one thread per 16B unit.
__global__ void dnimg_kernel(const float* __restrict__ dn, unsigned short* __restrict__ dnimg) {
    int idx = blockIdx.x * 256 + threadIdx.x;      // NE*2*6*1536 = 73728
    int L = idx % 1536;
    int r = idx / 1536;
    int kt = r % 6; r /= 6;
    int half = r & 1; int e = r >> 1;
    int colp = L >> 3, slot = L & 7;
    int v = slot ^ (colp & 7);
    int tc = colp * 2 + (v >> 2);                  // h-col within half (0..383)
    int kb = kt * 32 + (v & 3) * 8;                // f-index (0..191)
    const float* src = dn + ((size_t)(e * F1 + kb)) * HD + half * 384 + tc;
    unsigned short o[8];
    #pragma unroll
    for (int j = 0; j < 8; ++j) o[j] = f2bf(src[(size_t)j * HD]);
    *(bf16x8*)(dnimg + ((size_t)idx) * 8) = *(const bf16x8*)o;
}

__global__ __launch_bounds__(512, 1)
void moe_kernel(const float* __restrict__ hidden, const int* __restrict__ counts,
                const int* __restrict__ bucket, const unsigned short* __restrict__ b1img,
                const unsigned short* __restrict__ dnimg, float* __restrict__ out)
{
    extern __shared__ __align__(16) unsigned char smem[];
    const unsigned LAo[2] = {0u, 8192u};
    const unsigned LBo[4] = {16384u, 40960u, 65536u, 90112u};
    const unsigned LCo[3] = {49152u, 73728u, 98304u};
    const unsigned LACT = 0u;

    // exact block -> (expert, tile) mapping via prefix over counts
    int rem = blockIdx.x, e, n_e = 0;
    for (e = 0; e < NE; ++e) {
        n_e = counts[e];
        int ntiles = (n_e + TT - 1) >> 7;
        if (rem < ntiles) break;
        rem -= ntiles;
    }
    if (e >= NE) return;
    int t0 = rem << 7;

    int tid = threadIdx.x;
    int lane = tid & 63;
    int w = tid >> 6;
    int rw64 = (w >> 2) << 6;      // row half 0/64
    int cq = w & 3;                // col quarter
    int lg = lane >> 4;
    int l16 = lane & 15;

    int* tokp = (int*)(smem + LTOK);
    if (tid < TT) {
        int idx = t0 + tid; if (idx >= n_e) idx = n_e - 1;
        tokp[tid] = bucket[e * NT + idx];
    }
    __syncthreads();

    // ---- A staging: thread -> (row=tid>>2, kq=tid&3), 8 fp32 per step ----
    int arow = tid >> 2, kq = tid & 3;
    const float* aptr = hidden + (size_t)tokp[arow] * HD + kq * 8;
    unsigned awb = (unsigned)((tid >> 3) * 128 +
                   (((kq + ((arow & 1) << 2)) ^ ((tid >> 3) & 7)) << 4));

    // ---- B1 / B2 GLL: 3 wave-loads/step from pre-swizzled images ----
    const unsigned short* gls  = b1img + (size_t)e * 24 * 12288 + (w * 3) * 512 + lane * 8;
    const unsigned short* gls2 = dnimg + (size_t)e * 12 * 12288 + (w * 3) * 512 + lane * 8;
    unsigned gld = (unsigned)(w * 3) * 1024u;

    // ---- fragment read addressing (slot-XOR, proven 0-conflict) ----
    unsigned laneoff = (unsigned)(((l16 >> 1) << 7) +
                       (((lg + ((l16 & 1) << 2)) ^ (l16 >> 1)) << 4));
    unsigned arb[4], brb[6], b2rb[6];
    #pragma unroll
    for (int mt = 0; mt < 4; ++mt)
        arb[mt] = (unsigned)((rw64 + mt * 16) * 64) + laneoff;
    #pragma unroll
    for (int nt = 0; nt < 6; ++nt) {
        int tcb = (nt < 3) ? (cq * 48 + nt * 16) : (192 + cq * 48 + (nt - 3) * 16);
        brb[nt] = (unsigned)(tcb * 64) + laneoff;
        b2rb[nt] = (unsigned)((cq * 96 + nt * 16) * 64) + laneoff;
    }

    f32x4 avb[2][2];
    const f32x4 fzero = {0.f, 0.f, 0.f, 0.f};
    f32x4 acc[4][6];
    #pragma unroll
    for (int mt = 0; mt < 4; ++mt)
        #pragma unroll
        for (int nt = 0; nt < 6; ++nt) acc[mt][nt] = fzero;

    // ================= GEMM1: C1[128][384], K=768, BK=32, 2-deep counted-vmcnt =================
    // prologue: A(0),A(1) -> regs; B(0),B(1) -> LDS; writeA(0)
    {
        const f32x4* p0 = (const f32x4*)(aptr);
        avb[0][0] = p0[0]; avb[0][1] = p0[1];
        const f32x4* p1 = (const f32x4*)(aptr + 32);
        avb[1][0] = p1[0]; avb[1][1] = p1[1];
        #pragma unroll
        for (int i = 0; i < 3; ++i) GLL(gls + i * 512, LBo[0] + gld + i * 1024u);
        #pragma unroll
        for (int i = 0; i < 3; ++i) GLL(gls + 12288 + i * 512, LBo[1] + gld + i * 1024u);
        u32x4 vv = {pk2(avb[0][0].x,avb[0][0].y), pk2(avb[0][0].z,avb[0][0].w),
                    pk2(avb[0][1].x,avb[0][1].y), pk2(avb[0][1].z,avb[0][1].w)};
        *(u32x4*)(smem + LAo[0] + awb) = vv;   // forces wait on A(0) only
        asm volatile("s_waitcnt vmcnt(3) lgkmcnt(0)");   // B(0) done; B(1) in flight
        __builtin_amdgcn_s_barrier();
        __builtin_amdgcn_sched_barrier(0);
    }

    #pragma unroll
    for (int g = 0; g < 24; ++g) {
        if (g < 22) {
            // issue A(g+2) -> avb[g&1] (freed: its prior content was written at step g-1)
            const f32x4* p = (const f32x4*)(aptr + (g + 2) * 32);
            avb[g & 1][0] = p[0]; avb[g & 1][1] = p[1];
            // issue B(g+2) -> LB[(g+2)&3]
            #pragma unroll
            for (int i = 0; i < 3; ++i)
                GLL(gls + (size_t)(g + 2) * 12288 + i * 512, LBo[(g + 2) & 3] + gld + i * 1024u);
        }

        // compute step g from LA[g&1], LB[g&3]
        bf16x8 Af[4];
        #pragma unroll
        for (int mt = 0; mt < 4; ++mt)
            Af[mt] = *(const bf16x8*)(smem + LAo[g & 1] + arb[mt]);
        __builtin_amdgcn_s_setprio(1);
        #pragma unroll
        for (int nt = 0; nt < 6; ++nt) {
            bf16x8 Bf = *(const bf16x8*)(smem + LBo[g & 3] + brb[nt]);
            #pragma unroll
            for (int mt = 0; mt < 4; ++mt)
                acc[mt][nt] = __builtin_amdgcn_mfma_f32_16x16x32_bf16(Af[mt], Bf, acc[mt][nt], 0, 0, 0);
        }
        __builtin_amdgcn_s_setprio(0);

        if (g < 23) {
            // writeA(g+1): consumes avb[(g+1)&1] (loaded at step g-1) -> counted implicit wait
            f32x4 a0 = avb[(g + 1) & 1][0], a1 = avb[(g + 1) & 1][1];
            u32x4 vv = {pk2(a0.x,a0.y), pk2(a0.z,a0.w), pk2(a1.x,a1.y), pk2(a1.z,a1.w)};
            *(u32x4*)(smem + LAo[(g + 1) & 1] + awb) = vv;
            // boundary: B(g+1) must be done; keep A(g+2)+B(g+2) (5 loads) in flight
            if (g < 22) asm volatile("s_waitcnt vmcnt(5) lgkmcnt(0)");
            else        asm volatile("s_waitcnt vmcnt(0) lgkmcnt(0)");
            __builtin_amdgcn_s_barrier();
            __builtin_amdgcn_sched_barrier(0);
        }
    }

    // barrier: all waves done reading B1/A before act overwrites those regions
    asm volatile("s_waitcnt lgkmcnt(0)");
    __builtin_amdgcn_s_barrier();
    __builtin_amdgcn_sched_barrier(0);

    // ================= act = silu(gate)*up -> LDS ; prefetch B2(0),B2(1) =================
    #pragma unroll
    for (int i = 0; i < 3; ++i) GLL(gls2 + i * 512, LCo[0] + gld + i * 1024u);
    #pragma unroll
    for (int i = 0; i < 3; ++i) GLL(gls2 + 12288 + i * 512, LCo[1] + gld + i * 1024u);

    #pragma unroll
    for (int mt = 0; mt < 4; ++mt)
        #pragma unroll
        for (int nt = 0; nt < 3; ++nt)
            #pragma unroll
            for (int p = 0; p < 4; ++p) {
                float g = acc[mt][nt][p];
                float u = acc[mt][nt + 3][p];
                float s = g / (1.f + __expf(-g));
                int row = rw64 + mt * 16 + 4 * lg + p;
                int f = cq * 48 + nt * 16 + l16;
                int c = f >> 3;
                unsigned b = (unsigned)(LACT + row * 384 + (((c & 24) | ((c & 7) ^ (row & 7))) << 4) + (f & 7) * 2);
                *(unsigned short*)(smem + b) = f2bf(s * u);
            }
    asm volatile("s_waitcnt vmcnt(3) lgkmcnt(0)");   // B2(0) done; B2(1) in flight
    __builtin_amdgcn_s_barrier();
    __builtin_amdgcn_sched_barrier(0);

    // ================= GEMM2: out[128][768] = act[128][192] * down, 2-deep =================
    #pragma unroll
    for (int half = 0; half < 2; ++half) {
        f32x4 c2[4][6];
        #pragma unroll
        for (int mt = 0; mt < 4; ++mt)
            #pragma unroll
            for (int nt = 0; nt < 6; ++nt) c2[mt][nt] = fzero;

        #pragma unroll
        for (int kt = 0; kt < 6; ++kt) {
            const int s = half * 6 + kt;
            if (s < 10) {
                #pragma unroll
                for (int i = 0; i < 3; ++i)
                    GLL(gls2 + (size_t)(s + 2) * 12288 + i * 512, LCo[(s + 2) % 3] + gld + i * 1024u);
            }

            int c = kt * 4 + lg;
            unsigned a2sl = (unsigned)(((c & 24) | ((c & 7) ^ (l16 & 7))) << 4);
            bf16x8 A2[4];
            #pragma unroll
            for (int mt = 0; mt < 4; ++mt)
                A2[mt] = *(const bf16x8*)(smem + LACT + (rw64 + mt * 16 + l16) * 384 + a2sl);
            __builtin_amdgcn_s_setprio(1);
            #pragma unroll
            for (int nt = 0; nt < 6; ++nt) {
                bf16x8 B2f = *(const bf16x8*)(smem + LCo[s % 3] + b2rb[nt]);
                #pragma unroll
                for (int mt = 0; mt < 4; ++mt)
                    c2[mt][nt] = __builtin_amdgcn_mfma_f32_16x16x32_bf16(A2[mt], B2f, c2[mt][nt], 0, 0, 0);
            }
            __builtin_amdgcn_s_setprio(0);

            if (s < 11) {
                if (s < 10) asm volatile("s_waitcnt vmcnt(3) lgkmcnt(0)");
                else        asm volatile("s_waitcnt vmcnt(0) lgkmcnt(0)");
                __builtin_amdgcn_s_barrier();
                __builtin_amdgcn_sched_barrier(0);
            }
        }

        #pragma unroll
        for (int mt = 0; mt < 4; ++mt)
            #pragma unroll
            for (int p = 0; p < 4; ++p) {
                int row = rw64 + mt * 16 + 4 * lg + p;
                if (t0 + row < n_e) {
                    float* orow = out + (size_t)tokp[row] * HD + half * 384 + cq * 96 + l16;
                    #pragma unroll
                    for (int nt = 0; nt < 6; ++nt)
                        orow[nt * 16] = c2[mt][nt][p];
                }
            }
    }
}

extern "C" void kernel_launch(void* const* d_in, const int* in_sizes, int n_in,
                              void* d_out, int out_size, void* d_ws, size_t ws_size,
                              hipStream_t stream) {
    (void)in_sizes; (void)n_in; (void)out_size; (void)ws_size;
    const float* hidden = (const float*)d_in[0];
    const int*   ids    = (const int*)d_in[1];
    const float* gu     = (const float*)d_in[2];
    const float* dn     = (const float*)d_in[3];
    float* out = (float*)d_out;

    char* ws = (char*)d_ws;
    int* counts = (int*)ws;
    int* bucket = (int*)(ws + WS_BUCKET_OFF);
    unsigned short* b1img = (unsigned short*)(ws + WS_B1IMG_OFF);
    unsigned short* dnimg = (unsigned short*)(ws + WS_DNIMG_OFF);

    hipMemsetAsync(d_ws, 0, 64, stream);
    route_kernel<<<NT / 256, 256, 0, stream>>>(ids, counts, bucket);
    b1img_kernel<<<576, 256, 0, stream>>>(gu, b1img);       // NE*24*1536 units
    dnimg_kernel<<<288, 256, 0, stream>>>(dn, dnimg);       // NE*2*6*1536 units
    moe_kernel<<<1028, 512, SMEM_BYTES, stream>>>(hidden, counts, bucket, b1img, dnimg, out);
}